// Round 7
// baseline (118.968 us; speedup 1.0000x reference)
//
#include <hip/hip_runtime.h>
#include <math.h>

// Problem constants
#define BB 16      // batch
#define LL 32      // L
#define AA 2046    // attributor cols
#define MM 2048    // M = A + 2
#define NROWS 192  // 6L
#define CT 128     // column tiles
#define CPB 16     // columns per block (c-space)

// c-space mapping: c in [0,2045] -> n = c+1 (att col c); c=2046 -> n=0 (user
// column, no W1); c=2047 -> n=M-1 (item column, no W1).
//
// Round-7 = round-3 lean body, tile quartered for TLP:
//   2048 blocks (8 blocks/CU = 32 waves/CU) x 256 thr; per thread 2 cols x
//   (4 st-rows + 2 value-rows), in-loop loads, a[2][2] accumulators ->
//   VGPR stays < 64 so the full 8 waves/SIMD are resident (rule: waves
//   halve at 64 VGPR). Goal: hide post-poison ~900cy cold HBM misses.

__global__ __launch_bounds__(256) void fused_kernel(
    const float* __restrict__ user, const float* __restrict__ item,
    const float* __restrict__ att, const float* __restrict__ adj,
    const float* __restrict__ iw, const float* __restrict__ W1,
    const float* __restrict__ W2, float* __restrict__ out) {
  const int ctile = blockIdx.x, b = blockIdx.y, tid = threadIdx.x;
  __shared__ float KQ[4][LL];
  __shared__ float uvs[4][64];
  __shared__ float stS[32][8][2][2];  // [rowgroup][colquad][colInPair][j]
  __shared__ float cs[2][CPB];
  __shared__ float gred[32][2][2];    // [rowgroup][rowInGroup][j]

  const int cq = tid & 7, rg = tid >> 3;
  const int c0 = ctile * CPB + cq * 2;
  const bool tail = (c0 >= AA);  // only ctile==127, cq==7: cols 2046,2047

  // ---- prep stage 1: K/Q boundary projections ----
  if (tid < 128) {
    const int q = tid >> 5, l = tid & 31;
    const float* __restrict__ src = (q == 0 || q == 2) ? user : item;
    const int rbase = (q < 2) ? 64 : 0;  // K rows 64..127, Q rows 0..63
    float acc = 0.f;
#pragma unroll
    for (int r = 0; r < 64; ++r)
      acc += fmaxf(src[b * NROWS + rbase + r], 0.f) * W2[(rbase + r) * LL + l];
    KQ[q][l] = acc;  // 0:K0(user) 1:K1(item) 2:Q0(user) 3:Q1(item)
  }
  __syncthreads();
  {  // ---- prep stage 2: u/v weights ----
    const int which = tid >> 6, r = tid & 63;
    const int wrow = (which < 2) ? r : 64 + r;
    float acc = 0.f;
#pragma unroll
    for (int l = 0; l < LL; ++l) acc += W2[wrow * LL + l] * KQ[which][l];
    uvs[which][r] = acc;  // 0:u0 1:u1 2:v0 3:v1
  }
  __syncthreads();

  // ---- s/t partials: col-pair x 4-row group, in-loop loads ----
  {
    const float* __restrict__ wj0 = uvs[(rg < 16) ? 0 : 2];
    const float* __restrict__ wj1 = uvs[(rg < 16) ? 1 : 3];
    const int rbase = (rg < 16) ? 0 : 64;  // s: Q rows 0..63, t: K rows 64..127
    const int rrow0 = (rg & 15) * 4 + rbase;
    float a[2][2] = {};  // [colInPair][j]
#pragma unroll
    for (int i = 0; i < 4; ++i) {
      const int r = rrow0 + i;
      const int widx = r - rbase;
      float v0, v1;
      if (!tail) {
        const float2 av =
            *(const float2*)(att + (size_t)(b * NROWS + r) * AA + c0);
        const float2 wv = *(const float2*)(W1 + (size_t)r * AA + c0);
        v0 = fmaxf(av.x * wv.x, 0.f);
        v1 = fmaxf(av.y * wv.y, 0.f);
      } else {  // c 2046 -> user (n=0), 2047 -> item (n=M-1)
        v0 = fmaxf(user[b * NROWS + r], 0.f);
        v1 = fmaxf(item[b * NROWS + r], 0.f);
      }
      const float u0 = wj0[widx], u1 = wj1[widx];
      a[0][0] += v0 * u0;
      a[0][1] += v0 * u1;
      a[1][0] += v1 * u0;
      a[1][1] += v1 * u1;
    }
    *(float4*)&stS[rg][cq][0][0] = make_float4(a[0][0], a[0][1], a[1][0], a[1][1]);
  }
  __syncthreads();

  // ---- cweight: 16 cols x 2 targets ----
  if (tid < 32) {
    const int col = tid >> 1, j = tid & 1;
    const int q = col >> 1, ci = col & 1;
    float s = 0.f, t = 0.f;
#pragma unroll
    for (int g = 0; g < 16; ++g) s += stS[g][q][ci][j];
#pragma unroll
    for (int g = 16; g < 32; ++g) t += stS[g][q][ci][j];
    const int cc = ctile * CPB + col;
    const int n = (cc < AA) ? cc + 1 : ((cc == AA) ? 0 : MM - 1);
    const size_t tcol = j ? (MM - 1) : 0;
    const float an = adj[(size_t)n * MM + tcol];
    const float wn = an * iw[(size_t)n * MM + tcol];
    const float wt = adj[tcol * MM + n] * iw[tcol * MM + n];
    const float d = s * wn - t * wt;
    const float e = expf(-fabsf(d));
    const float sig = (d > 0.f) ? 1.f / (1.f + e) : e / (1.f + e);
    cs[j][col] = sig * an;
  }
  __syncthreads();

  // ---- value: col-pair x 2-row group over rows 128..191 ----
  {
    const float c00 = cs[0][cq * 2], c01 = cs[0][cq * 2 + 1];
    const float c10 = cs[1][cq * 2], c11 = cs[1][cq * 2 + 1];
    float g[2][2];
#pragma unroll
    for (int i = 0; i < 2; ++i) {
      const int r = 128 + rg * 2 + i;
      float v0, v1;
      if (!tail) {
        const float2 av =
            *(const float2*)(att + (size_t)(b * NROWS + r) * AA + c0);
        const float2 wv = *(const float2*)(W1 + (size_t)r * AA + c0);
        v0 = fmaxf(av.x * wv.x, 0.f);
        v1 = fmaxf(av.y * wv.y, 0.f);
      } else {
        v0 = fmaxf(user[b * NROWS + r], 0.f);
        v1 = fmaxf(item[b * NROWS + r], 0.f);
      }
      g[i][0] = v0 * c00 + v1 * c01;
      g[i][1] = v0 * c10 + v1 * c11;
    }
    // reduce over the 8 col-pairs (cq spans consecutive lanes within 8)
#pragma unroll
    for (int m = 4; m >= 1; m >>= 1) {
#pragma unroll
      for (int i = 0; i < 2; ++i) {
        g[i][0] += __shfl_xor(g[i][0], m, 8);
        g[i][1] += __shfl_xor(g[i][1], m, 8);
      }
    }
    if (cq == 0) {
#pragma unroll
      for (int i = 0; i < 2; ++i) {
        gred[rg][i][0] = g[i][0];
        gred[rg][i][1] = g[i][1];
      }
    }
  }
  __syncthreads();

  // ---- project partial g through W2, atomic-accumulate ----
  if (tid < 64) {
    const int l = tid & 31, j = tid >> 5;
    float acc = 0.f;
#pragma unroll
    for (int rv = 0; rv < 64; ++rv)
      acc += W2[(128 + rv) * LL + l] * gred[rv >> 1][rv & 1][j];
    atomicAdd(&out[b * (LL * 2) + l * 2 + j], acc);
  }
}

extern "C" void kernel_launch(void* const* d_in, const int* in_sizes, int n_in,
                              void* d_out, int out_size, void* d_ws,
                              size_t ws_size, hipStream_t stream) {
  const float* user = (const float*)d_in[0];
  const float* item = (const float*)d_in[1];
  const float* att = (const float*)d_in[2];
  const float* adj = (const float*)d_in[3];
  const float* iw = (const float*)d_in[4];
  const float* W1 = (const float*)d_in[5];
  const float* W2 = (const float*)d_in[6];
  float* out = (float*)d_out;

  hipMemsetAsync(d_out, 0, sizeof(float) * (size_t)out_size, stream);
  fused_kernel<<<dim3(CT, BB), 256, 0, stream>>>(user, item, att, adj, iw, W1,
                                                 W2, out);
}

// Round 8
// 108.859 us; speedup vs baseline: 1.0929x; 1.0929x over previous
//
#include <hip/hip_runtime.h>
#include <math.h>

// Problem constants
#define BB 16      // batch
#define LL 32      // L
#define AA 2046    // attributor cols
#define MM 2048    // M = A + 2
#define NROWS 192  // 6L
#define CT 32      // column tiles
#define CPB 64     // columns per block (c-space)

// c-space mapping: c in [0,2045] -> n = c+1 (att col c); c=2046 -> n=0 (user
// column, no W1); c=2047 -> n=M-1 (item column, no W1). This keeps att float2
// loads 8B-aligned and makes the value phase use the same layout as s/t.
//
// Round-8 = verbatim restore of the round-3 champion (108.1 µs), the best
// point of the explored space: occupancy 8 waves/CU, single dispatch,
// in-loop loads. Variants measured: CPB=32 merged loads 111.9, hoisted
// 110.3, CPB=16/32-waves 119.0, 2-dispatch 113.9, 4-dispatch 113.0.

// ---------------------------------------------------------------------------
// Single fused kernel (plus a 4KB memset). grid (32 ctiles, 16 b) x 256 thr.
// Per block (owns 64 c-space columns, everything stays in LDS):
//   prep    : redundant K/Q projections -> u_j[64], v_j[64] weights
//   st      : thread (cq=tid&15, rg=tid>>4) = col-quad x 8-row group over
//             rows 0..127 -> partial s/t dots in stS
//   cweight : 128 threads combine -> cs[j][64] = sigmoid(d_j)*adj  (LDS only)
//   value   : thread (cq, rg) = col-quad x 4-row group over rows 128..191,
//             g_j[r] partials; shuffle-reduce over the 16 col-quads
//   project : 64 threads: partial out[b,l,j] = sum_r W2[128+r,l]*g_j[r],
//             one atomicAdd per (block,l,j)
// ---------------------------------------------------------------------------
__global__ __launch_bounds__(256) void fused_kernel(
    const float* __restrict__ user, const float* __restrict__ item,
    const float* __restrict__ att, const float* __restrict__ adj,
    const float* __restrict__ iw, const float* __restrict__ W1,
    const float* __restrict__ W2, float* __restrict__ out) {
  const int ctile = blockIdx.x, b = blockIdx.y, tid = threadIdx.x;
  __shared__ float KQ[4][LL];
  __shared__ float uvs[4][64];
  __shared__ float stS[16][16][4][2];  // [rowgroup][colquad][colInQuad][j]
  __shared__ float cs[2][CPB];
  __shared__ float gred[16][4][2];     // [rowgroup][rowInGroup][j]

  // ---- prep stage 1: K/Q boundary projections ----
  if (tid < 128) {
    const int q = tid >> 5, l = tid & 31;
    const float* __restrict__ src = (q == 0 || q == 2) ? user : item;
    const int rbase = (q < 2) ? 64 : 0;  // K rows 64..127, Q rows 0..63
    float acc = 0.f;
#pragma unroll
    for (int r = 0; r < 64; ++r)
      acc += fmaxf(src[b * NROWS + rbase + r], 0.f) * W2[(rbase + r) * LL + l];
    KQ[q][l] = acc;  // 0:K0(user) 1:K1(item) 2:Q0(user) 3:Q1(item)
  }
  __syncthreads();
  {  // ---- prep stage 2: u/v weights ----
    const int which = tid >> 6, r = tid & 63;
    const int wrow = (which < 2) ? r : 64 + r;
    float acc = 0.f;
#pragma unroll
    for (int l = 0; l < LL; ++l) acc += W2[wrow * LL + l] * KQ[which][l];
    uvs[which][r] = acc;  // 0:u0 1:u1 2:v0 3:v1
  }
  __syncthreads();

  // ---- s/t partials: col-quad x 8-row group ----
  {
    const int cq = tid & 15, rg = tid >> 4;
    const int c0 = ctile * CPB + cq * 4;
    const float* __restrict__ wj0 = uvs[(rg < 8) ? 0 : 2];
    const float* __restrict__ wj1 = uvs[(rg < 8) ? 1 : 3];
    const int rbase = (rg < 8) ? 0 : 64;
    const int rrow0 = (rg & 7) * 8 + rbase;
    float a[4][2] = {};
#pragma unroll
    for (int i = 0; i < 8; ++i) {
      const int r = rrow0 + i;
      const int widx = r - rbase;
      const size_t arow = (size_t)(b * NROWS + r) * AA;
      const size_t wrow = (size_t)r * AA;
      const float2 av0 = *(const float2*)(att + arow + c0);
      const float2 wv0 = *(const float2*)(W1 + wrow + c0);
      const float v0 = fmaxf(av0.x * wv0.x, 0.f);
      const float v1 = fmaxf(av0.y * wv0.y, 0.f);
      float v2, v3;
      if (c0 + 2 < AA) {
        const float2 av1 = *(const float2*)(att + arow + c0 + 2);
        const float2 wv1 = *(const float2*)(W1 + wrow + c0 + 2);
        v2 = fmaxf(av1.x * wv1.x, 0.f);
        v3 = fmaxf(av1.y * wv1.y, 0.f);
      } else {  // tail quad: c 2046 -> user, 2047 -> item (no W1)
        v2 = fmaxf(user[b * NROWS + r], 0.f);
        v3 = fmaxf(item[b * NROWS + r], 0.f);
      }
      const float u0 = wj0[widx], u1 = wj1[widx];
      a[0][0] += v0 * u0; a[0][1] += v0 * u1;
      a[1][0] += v1 * u0; a[1][1] += v1 * u1;
      a[2][0] += v2 * u0; a[2][1] += v2 * u1;
      a[3][0] += v3 * u0; a[3][1] += v3 * u1;
    }
#pragma unroll
    for (int k = 0; k < 4; ++k) {
      stS[rg][cq][k][0] = a[k][0];
      stS[rg][cq][k][1] = a[k][1];
    }
  }
  __syncthreads();

  // ---- cweight: 64 cols x 2 targets ----
  if (tid < 128) {
    const int col = tid >> 1, j = tid & 1;
    const int cq = col >> 2, ci = col & 3;
    float s = 0.f, t = 0.f;
#pragma unroll
    for (int rg = 0; rg < 8; ++rg) s += stS[rg][cq][ci][j];
#pragma unroll
    for (int rg = 8; rg < 16; ++rg) t += stS[rg][cq][ci][j];
    const int cc = ctile * CPB + col;
    const int n = (cc < AA) ? cc + 1 : ((cc == AA) ? 0 : MM - 1);
    const size_t tcol = j ? (MM - 1) : 0;
    const float an = adj[(size_t)n * MM + tcol];
    const float wn = an * iw[(size_t)n * MM + tcol];
    const float wt = adj[tcol * MM + n] * iw[tcol * MM + n];
    const float d = s * wn - t * wt;
    const float e = expf(-fabsf(d));
    const float sig = (d > 0.f) ? 1.f / (1.f + e) : e / (1.f + e);
    cs[j][col] = sig * an;
  }
  __syncthreads();

  // ---- value gather: col-quad x 4-row group over rows 128..191 ----
  {
    const int cq = tid & 15, rg = tid >> 4;
    const int c0 = ctile * CPB + cq * 4;
    const float c00 = cs[0][cq * 4], c01 = cs[0][cq * 4 + 1];
    const float c02 = cs[0][cq * 4 + 2], c03 = cs[0][cq * 4 + 3];
    const float c10 = cs[1][cq * 4], c11 = cs[1][cq * 4 + 1];
    const float c12 = cs[1][cq * 4 + 2], c13 = cs[1][cq * 4 + 3];
    float g[4][2] = {};
#pragma unroll
    for (int i = 0; i < 4; ++i) {
      const int r = 128 + rg * 4 + i;
      const size_t arow = (size_t)(b * NROWS + r) * AA;
      const size_t wrow = (size_t)r * AA;
      const float2 av0 = *(const float2*)(att + arow + c0);
      const float2 wv0 = *(const float2*)(W1 + wrow + c0);
      const float v0 = fmaxf(av0.x * wv0.x, 0.f);
      const float v1 = fmaxf(av0.y * wv0.y, 0.f);
      float v2, v3;
      if (c0 + 2 < AA) {
        const float2 av1 = *(const float2*)(att + arow + c0 + 2);
        const float2 wv1 = *(const float2*)(W1 + wrow + c0 + 2);
        v2 = fmaxf(av1.x * wv1.x, 0.f);
        v3 = fmaxf(av1.y * wv1.y, 0.f);
      } else {
        v2 = fmaxf(user[b * NROWS + r], 0.f);
        v3 = fmaxf(item[b * NROWS + r], 0.f);
      }
      g[i][0] += v0 * c00 + v1 * c01 + v2 * c02 + v3 * c03;
      g[i][1] += v0 * c10 + v1 * c11 + v2 * c12 + v3 * c13;
    }
    // reduce over the 16 col-quads (lanes xor 1,2,4,8 within 16-lane groups)
#pragma unroll
    for (int m = 8; m >= 1; m >>= 1) {
#pragma unroll
      for (int i = 0; i < 4; ++i) {
        g[i][0] += __shfl_xor(g[i][0], m, 16);
        g[i][1] += __shfl_xor(g[i][1], m, 16);
      }
    }
    if (cq == 0) {
#pragma unroll
      for (int i = 0; i < 4; ++i) {
        gred[rg][i][0] = g[i][0];
        gred[rg][i][1] = g[i][1];
      }
    }
  }
  __syncthreads();

  // ---- project partial g through W2, atomic-accumulate ----
  if (tid < 64) {
    const int l = tid & 31, j = tid >> 5;
    float acc = 0.f;
#pragma unroll
    for (int rv = 0; rv < 64; ++rv)
      acc += W2[(128 + rv) * LL + l] * gred[rv >> 2][rv & 3][j];
    atomicAdd(&out[b * (LL * 2) + l * 2 + j], acc);
  }
}

extern "C" void kernel_launch(void* const* d_in, const int* in_sizes, int n_in,
                              void* d_out, int out_size, void* d_ws,
                              size_t ws_size, hipStream_t stream) {
  const float* user = (const float*)d_in[0];
  const float* item = (const float*)d_in[1];
  const float* att = (const float*)d_in[2];
  const float* adj = (const float*)d_in[3];
  const float* iw = (const float*)d_in[4];
  const float* W1 = (const float*)d_in[5];
  const float* W2 = (const float*)d_in[6];
  float* out = (float*)d_out;

  hipMemsetAsync(d_out, 0, sizeof(float) * (size_t)out_size, stream);
  fused_kernel<<<dim3(CT, BB), 256, 0, stream>>>(user, item, att, adj, iw, W1,
                                                 W2, out);
}